// Round 19
// baseline (1763.906 us; speedup 1.0000x reference)
//
#include <hip/hip_runtime.h>

#define N_USERS 1000000
#define NEDGE   32000000
#define OUT_F   64
#define BN_EPS  1e-5f

// ---- Pass 1 (proven round-12 scatter): 245 dst-buckets of 4096 ----
#define SBITS     12
#define S_BUCKET  4096
#define NB        245
#define CAP       136896                  // mean 130612 + ~17 sigma, mult of 16
#define SCAT_BLOCKS 1024
#define TILE      4096
#define NTILES    ((NEDGE + TILE - 1) / TILE)

// ---- Pass 2 (regroup): super-buckets x src-windows ----
// Hop is load-latency-bound (round-18: VALUBusy 3.9%). Controlling variable:
// waves/CU x records-in-flight/lane vs ~600cyc L3 latency on the record
// stream. This round: acc 96KB->48KB (2-3 blocks/CU instead of 1), HSPLIT 8,
// wave-private windows (round-17 structure, no barriers), 16-deep record MLP.
#define SUP_B     3                       // pass-1 buckets per super
#define NSUP      82                      // ceil(245/3)
#define S_SUPER   12288                   // dst nodes per super (acc = 48KB LDS)
#define NWIN      245                     // src windows of 4096 (src>>12)
#define NBINS2    (NSUP * NWIN)           // 20090
#define HSPLIT    8                       // blocks per super in the hop
#define RGRID     1024
#define MT        34                      // max tiles per bucket (34*4096 >= CAP)

static_assert((unsigned long long)NEDGE * 8ull ==
              (unsigned long long)N_USERS * OUT_F * 4ull,
              "compact rec2 must exactly fit d_out");

typedef unsigned int uint4v __attribute__((ext_vector_type(4)));
typedef unsigned int uint2v __attribute__((ext_vector_type(2)));
typedef int          int4v  __attribute__((ext_vector_type(4)));
typedef float        flt4v  __attribute__((ext_vector_type(4)));

// ---------------- pass 1: binned scatter (unchanged from round 12) ----------------

__global__ void init_cursors(unsigned* __restrict__ cursors) {
    int i = blockIdx.x * blockDim.x + threadIdx.x;
    if (i < NB) cursors[i] = (unsigned)i * CAP;
}

__global__ __launch_bounds__(256) void scatter_bin(
    const int* __restrict__ src, const int* __restrict__ dst,
    const float* __restrict__ ew, uint2* __restrict__ rec,
    unsigned* __restrict__ cursors) {
    __shared__ uint2 srec[TILE];
    __shared__ unsigned short sbkt[TILE];
    __shared__ unsigned hist[NB];
    __shared__ unsigned curs[NB];
    __shared__ unsigned gpos[NB];
    __shared__ unsigned chunkT[256];
    int tid = threadIdx.x;

    for (int tile = blockIdx.x; tile < NTILES; tile += gridDim.x) {
        int e0 = tile * TILE;
        int n_this = (e0 + TILE <= NEDGE) ? TILE : (NEDGE - e0);
        int nq = n_this >> 2;
        int q0 = e0 >> 2;

        for (int i = tid; i < NB; i += 256) hist[i] = 0;
        __syncthreads();

        int4v dv[4]; int4v sv[4]; flt4v wv[4];
        #pragma unroll
        for (int k = 0; k < 4; ++k) {
            int q = k * 256 + tid;
            if (q < nq) {
                dv[k] = __builtin_nontemporal_load(reinterpret_cast<const int4v*>(dst) + q0 + q);
                sv[k] = __builtin_nontemporal_load(reinterpret_cast<const int4v*>(src) + q0 + q);
                wv[k] = __builtin_nontemporal_load(reinterpret_cast<const flt4v*>(ew) + q0 + q);
            }
        }
        #pragma unroll
        for (int k = 0; k < 4; ++k) {
            int q = k * 256 + tid;
            if (q < nq) {
                #pragma unroll
                for (int j = 0; j < 4; ++j)
                    atomicAdd(&hist[dv[k][j] >> SBITS], 1u);
            }
        }
        __syncthreads();

        {
            int base = tid * 4;
            unsigned run = 0;
            #pragma unroll
            for (int k = 0; k < 4; ++k) {
                int idx = base + k;
                unsigned v = (idx < NB) ? hist[idx] : 0u;
                if (idx < NB) hist[idx] = run;
                run += v;
            }
            chunkT[tid] = run;
        }
        __syncthreads();
        if (tid == 0) {
            unsigned r = 0;
            for (int t = 0; t < 256; ++t) { unsigned v = chunkT[t]; chunkT[t] = r; r += v; }
        }
        __syncthreads();
        {
            int base = tid * 4;
            unsigned add = chunkT[tid];
            #pragma unroll
            for (int k = 0; k < 4; ++k) {
                int idx = base + k;
                if (idx < NB) hist[idx] += add;
            }
        }
        __syncthreads();

        for (int b = tid; b < NB; b += 256) {
            unsigned st = hist[b];
            unsigned en = (b == NB - 1) ? (unsigned)n_this : hist[b + 1];
            unsigned c = en - st;
            gpos[b] = c ? atomicAdd(&cursors[b], c) : 0u;
            curs[b] = 0;
        }
        __syncthreads();

        #pragma unroll
        for (int k = 0; k < 4; ++k) {
            int q = k * 256 + tid;
            if (q < nq) {
                #pragma unroll
                for (int j = 0; j < 4; ++j) {
                    int dd = dv[k][j], ss = sv[k][j];
                    int b = dd >> SBITS;
                    unsigned p = hist[b] + atomicAdd(&curs[b], 1u);
                    srec[p] = make_uint2(((unsigned)(dd & (S_BUCKET - 1)) << 20) | (unsigned)ss,
                                         __float_as_uint(wv[k][j]));
                    sbkt[p] = (unsigned short)b;
                }
            }
        }
        __syncthreads();

        for (int i = tid; i < n_this; i += 256) {
            unsigned b = sbkt[i];
            rec[gpos[b] + ((unsigned)i - hist[b])] = srec[i];
        }
        __syncthreads();
    }
}

// ---------------- pass 2a: per-(super,window) counts (MLP) ----------------

__global__ __launch_bounds__(256) void count_bins(
    const uint2* __restrict__ rec, const unsigned* __restrict__ cursors,
    unsigned* __restrict__ cnt2) {
    __shared__ unsigned hist[NWIN];
    int tid = threadIdx.x;
    int b = blockIdx.x >> 2, q = blockIdx.x & 3;
    for (int i = tid; i < NWIN; i += 256) hist[i] = 0;
    __syncthreads();
    unsigned cnt = cursors[b] - (unsigned)b * CAP;
    unsigned lo = (unsigned)(((unsigned long long)cnt * (unsigned)q) >> 2) & ~1u;
    unsigned hi = (q == 3) ? (cnt & ~1u)
                           : ((unsigned)(((unsigned long long)cnt * (unsigned)(q + 1)) >> 2) & ~1u);
    const uint2* bp = rec + (size_t)b * CAP;

    unsigned i = lo + 2u * (unsigned)tid;
    for (; i + 1538u <= hi; i += 2048u) {        // 4x uint4v = 8 records in flight
        uint4v v0 = __builtin_nontemporal_load(reinterpret_cast<const uint4v*>(bp + i));
        uint4v v1 = __builtin_nontemporal_load(reinterpret_cast<const uint4v*>(bp + i + 512));
        uint4v v2 = __builtin_nontemporal_load(reinterpret_cast<const uint4v*>(bp + i + 1024));
        uint4v v3 = __builtin_nontemporal_load(reinterpret_cast<const uint4v*>(bp + i + 1536));
        atomicAdd(&hist[(v0.x & 0xFFFFFu) >> 12], 1u);
        atomicAdd(&hist[(v0.z & 0xFFFFFu) >> 12], 1u);
        atomicAdd(&hist[(v1.x & 0xFFFFFu) >> 12], 1u);
        atomicAdd(&hist[(v1.z & 0xFFFFFu) >> 12], 1u);
        atomicAdd(&hist[(v2.x & 0xFFFFFu) >> 12], 1u);
        atomicAdd(&hist[(v2.z & 0xFFFFFu) >> 12], 1u);
        atomicAdd(&hist[(v3.x & 0xFFFFFu) >> 12], 1u);
        atomicAdd(&hist[(v3.z & 0xFFFFFu) >> 12], 1u);
    }
    for (; i + 2u <= hi; i += 512u) {
        uint4v v = __builtin_nontemporal_load(reinterpret_cast<const uint4v*>(bp + i));
        atomicAdd(&hist[(v.x & 0xFFFFFu) >> 12], 1u);
        atomicAdd(&hist[(v.z & 0xFFFFFu) >> 12], 1u);
    }
    if (q == 3 && (cnt & 1u) && tid == 0) {      // odd tail record
        uint2v r = __builtin_nontemporal_load(
            reinterpret_cast<const uint2v*>(bp + (cnt - 1u)));
        atomicAdd(&hist[(r.x & 0xFFFFFu) >> 12], 1u);
    }
    __syncthreads();
    unsigned base = (unsigned)(b / SUP_B) * (unsigned)NWIN;
    for (int k = tid; k < NWIN; k += 256)
        if (hist[k]) atomicAdd(&cnt2[base + k], hist[k]);
}

// ---------------- pass 2b: exclusive prefix over 20090 bins ----------------

__global__ __launch_bounds__(256) void prefix_bins(
    const unsigned* __restrict__ cnt2, unsigned* __restrict__ bases,
    unsigned* __restrict__ cursors2) {
    __shared__ unsigned chunkT[256];
    int t = threadIdx.x;
    unsigned loc[79];
    unsigned run = 0;
    for (int k = 0; k < 79; ++k) {
        int idx = t * 79 + k;
        unsigned v = (idx < NBINS2) ? cnt2[idx] : 0u;
        loc[k] = run; run += v;
    }
    chunkT[t] = run;
    __syncthreads();
    if (t == 0) {
        unsigned r = 0;
        for (int i = 0; i < 256; ++i) { unsigned v = chunkT[i]; chunkT[i] = r; r += v; }
    }
    __syncthreads();
    unsigned add = chunkT[t];
    for (int k = 0; k < 79; ++k) {
        int idx = t * 79 + k;
        if (idx < NBINS2) { unsigned v = loc[k] + add; bases[idx] = v; cursors2[idx] = v; }
    }
    if (t == 0) bases[NBINS2] = (unsigned)NEDGE;
}

// ---------------- pass 2c: regroup into compact (super,window) segments ----------------
// meta2 = rdst(14b)<<12 | src_local(12b); rdst = (b%3)*4096 + dst_local.

__global__ __launch_bounds__(256) void regroup(
    const uint2* __restrict__ rec, const unsigned* __restrict__ cursors,
    uint2* __restrict__ rec2, unsigned* __restrict__ cursors2) {
    __shared__ uint2 srec[TILE];              // transformed records
    __shared__ unsigned char skey[TILE];
    __shared__ unsigned hist[NWIN];
    __shared__ unsigned curs[NWIN];
    __shared__ unsigned gpos[NWIN];
    __shared__ unsigned chunkT[256];
    int tid = threadIdx.x;

    for (int ti = blockIdx.x; ti < NB * MT; ti += gridDim.x) {
        int b = ti / MT;
        unsigned t = (unsigned)(ti % MT);
        unsigned cntb = cursors[b] - (unsigned)b * CAP;
        unsigned e0 = t * TILE;
        if (e0 >= cntb) continue;               // uniform per block
        unsigned n_this = (cntb - e0 < TILE) ? (cntb - e0) : TILE;
        unsigned binbase = (unsigned)(b / SUP_B) * (unsigned)NWIN;
        unsigned rb = (unsigned)(b % SUP_B) << 12;
        const uint2* bp = rec + (size_t)b * CAP;

        for (int i = tid; i < NWIN; i += 256) hist[i] = 0;
        __syncthreads();

        uint4v rv[8];                      // 16 records/thread
        #pragma unroll
        for (int k2 = 0; k2 < 8; ++k2) {
            unsigned idx = (unsigned)(k2 * 512 + tid * 2);
            if (idx < n_this)
                rv[k2] = __builtin_nontemporal_load(
                    reinterpret_cast<const uint4v*>(bp + e0 + idx));
        }
        #pragma unroll
        for (int k2 = 0; k2 < 8; ++k2) {
            unsigned idx = (unsigned)(k2 * 512 + tid * 2);
            if (idx < n_this)     atomicAdd(&hist[(rv[k2].x & 0xFFFFFu) >> 12], 1u);
            if (idx + 1 < n_this) atomicAdd(&hist[(rv[k2].z & 0xFFFFFu) >> 12], 1u);
        }
        __syncthreads();

        chunkT[tid] = (tid < NWIN) ? hist[tid] : 0u;
        __syncthreads();
        if (tid == 0) {
            unsigned r = 0;
            for (int i = 0; i < 256; ++i) { unsigned v = chunkT[i]; chunkT[i] = r; r += v; }
        }
        __syncthreads();
        if (tid < NWIN) hist[tid] = chunkT[tid];
        __syncthreads();
        if (tid < NWIN) {
            unsigned st = hist[tid];
            unsigned en = (tid == NWIN - 1) ? n_this : hist[tid + 1];
            unsigned c = en - st;
            gpos[tid] = c ? atomicAdd(&cursors2[binbase + tid], c) : 0u;
            curs[tid] = 0;
        }
        __syncthreads();

        #pragma unroll
        for (int k2 = 0; k2 < 8; ++k2) {
            unsigned idx = (unsigned)(k2 * 512 + tid * 2);
            if (idx < n_this) {
                unsigned m = rv[k2].x;
                unsigned k = (m & 0xFFFFFu) >> 12;
                unsigned p = hist[k] + atomicAdd(&curs[k], 1u);
                srec[p] = make_uint2((((m >> 20) + rb) << 12) | (m & 0xFFFu), rv[k2].y);
                skey[p] = (unsigned char)k;
            }
            if (idx + 1 < n_this) {
                unsigned m = rv[k2].z;
                unsigned k = (m & 0xFFFFFu) >> 12;
                unsigned p = hist[k] + atomicAdd(&curs[k], 1u);
                srec[p] = make_uint2((((m >> 20) + rb) << 12) | (m & 0xFFFu), rv[k2].w);
                skey[p] = (unsigned char)k;
            }
        }
        __syncthreads();

        for (unsigned i = (unsigned)tid; i < n_this; i += 256) {
            unsigned k = skey[i];
            rec2[gpos[k] + (i - hist[k])] = srec[i];
        }
        __syncthreads();
    }
}

// ---------------- hop: wave-private windows, 16-deep record MLP ----------------
// Each wave owns whole (super,window) cells (gathers in one 16KB L1-friendly
// window); 16 uint2 record loads in flight per lane hide the ~600cyc L2/L3
// record-stream latency. acc 48KB -> 2-3 blocks/CU. No barriers in main loop.

__global__ __launch_bounds__(512) void hop_super(
    const uint2* __restrict__ rec2, const unsigned* __restrict__ bases,
    const float* __restrict__ cur, float* __restrict__ nxt) {
    __shared__ float acc[S_SUPER];     // 48KB
    int tid = threadIdx.x;
    int s = blockIdx.x / HSPLIT;
    int j = blockIdx.x % HSPLIT;
    for (int i = tid; i < S_SUPER; i += 512) acc[i] = 0.0f;
    __syncthreads();

    int wid = tid >> 6;                // wave 0..7
    int lane = tid & 63;
    int slot = j * 8 + wid;            // 0..63 wave-slots per super
    const unsigned* bs = bases + s * NWIN;

    for (int k = slot; k < NWIN; k += HSPLIT * 8) {
        unsigned lo = bs[k];
        unsigned hi = bs[k + 1];       // flat prefix: valid sentinel for all k
        const float* win = cur + ((size_t)k << 12);
        unsigned i = lo + (unsigned)lane;
        for (; i + 15u * 64u < hi; i += 16u * 64u) {
            uint2 r[16];
            #pragma unroll
            for (int q = 0; q < 16; ++q) r[q] = rec2[i + (unsigned)q * 64u];
            float c[16];
            #pragma unroll
            for (int q = 0; q < 16; ++q) c[q] = win[r[q].x & 0xFFFu];
            #pragma unroll
            for (int q = 0; q < 16; ++q)
                atomicAdd(&acc[r[q].x >> 12], c[q] * __uint_as_float(r[q].y));
        }
        for (; i + 3u * 64u < hi; i += 4u * 64u) {
            uint2 r[4];
            #pragma unroll
            for (int q = 0; q < 4; ++q) r[q] = rec2[i + (unsigned)q * 64u];
            #pragma unroll
            for (int q = 0; q < 4; ++q)
                atomicAdd(&acc[r[q].x >> 12],
                          win[r[q].x & 0xFFFu] * __uint_as_float(r[q].y));
        }
        for (; i < hi; i += 64u) {
            uint2 r = rec2[i];
            atomicAdd(&acc[r.x >> 12], win[r.x & 0xFFFu] * __uint_as_float(r.y));
        }
    }
    __syncthreads();
    int d0 = s * S_SUPER;
    for (int i = tid; i < S_SUPER; i += 512) {
        int n = d0 + i;
        if (n < N_USERS) atomicAdd(&nxt[n], acc[i]);
    }
}

// ---------------- fallback path ----------------

__global__ void zero_kernel(float* __restrict__ p, int n) {
    int i = blockIdx.x * blockDim.x + threadIdx.x;
    int stride = gridDim.x * blockDim.x;
    for (; i < n; i += stride) p[i] = 0.0f;
}

__global__ __launch_bounds__(256) void hop_atomic(
    const int* __restrict__ src, const int* __restrict__ dst,
    const float* __restrict__ ew, const float* __restrict__ cur,
    float* __restrict__ nxt) {
    int e = blockIdx.x * blockDim.x + threadIdx.x;
    if (e * 4 < NEDGE) {
        int4   s = ((const int4*)src)[e];
        int4   d = ((const int4*)dst)[e];
        float4 w = ((const float4*)ew)[e];
        atomicAdd(&nxt[d.x], cur[s.x] * w.x);
        atomicAdd(&nxt[d.y], cur[s.y] * w.y);
        atomicAdd(&nxt[d.z], cur[s.z] * w.z);
        atomicAdd(&nxt[d.w], cur[s.w] * w.w);
    }
}

// ---------------- finalize ----------------

__global__ __launch_bounds__(256) void finalize_kernel(
    const float* __restrict__ x,  const float* __restrict__ f1,
    const float* __restrict__ f2, const float* __restrict__ f3,
    const float* __restrict__ f4, const float* __restrict__ W,
    const float* __restrict__ bias, const float* __restrict__ gamma,
    const float* __restrict__ beta, float* __restrict__ out) {
    int lane = threadIdx.x & 63;
    int waveInBlock = threadIdx.x >> 6;
    int wavesPerBlock = blockDim.x >> 6;
    int gwave  = blockIdx.x * wavesPerBlock + waveInBlock;
    int nwaves = gridDim.x * wavesPerBlock;

    float w0 = W[lane * 5 + 0];
    float w1 = W[lane * 5 + 1];
    float w2 = W[lane * 5 + 2];
    float w3 = W[lane * 5 + 3];
    float w4 = W[lane * 5 + 4];
    float b  = bias[lane];

    for (int n = gwave; n < N_USERS; n += nwaves) {
        float c0 = x[n], c1 = f1[n], c2 = f2[n], c3 = f3[n], c4 = f4[n];
        float y = b + c0 * w0 + c1 * w1 + c2 * w2 + c3 * w3 + c4 * w4;

        float s = y;
        #pragma unroll
        for (int off = 32; off; off >>= 1) s += __shfl_xor(s, off);
        float mean = s * (1.0f / 64.0f);

        float d = y - mean;
        float v = d * d;
        #pragma unroll
        for (int off = 32; off; off >>= 1) v += __shfl_xor(v, off);
        float var = v * (1.0f / 64.0f);

        float o = d * rsqrtf(var + BN_EPS) * gamma[n] + beta[n];
        __builtin_nontemporal_store(o, &out[(size_t)n * OUT_F + lane]);
    }
}

extern "C" void kernel_launch(void* const* d_in, const int* in_sizes, int n_in,
                              void* d_out, int out_size, void* d_ws, size_t ws_size,
                              hipStream_t stream) {
    const float* x     = (const float*)d_in[0];
    const int*   ei    = (const int*)d_in[1];
    const float* ew    = (const float*)d_in[2];
    const float* W     = (const float*)d_in[3];
    const float* bias  = (const float*)d_in[4];
    const float* gamma = (const float*)d_in[5];
    const float* beta  = (const float*)d_in[6];
    float* out = (float*)d_out;

    const int* src = ei;
    const int* dst = ei + NEDGE;

    // Workspace layout (~284.6MB; known-available >= 304MB from rounds 0-1)
    float* f = (float*)d_ws;                                     // 16MB
    uint2* rec = (uint2*)(f + 4ull * N_USERS);                   // 268.3MB
    unsigned* cursors  = (unsigned*)(rec + (size_t)NB * CAP);    // pad 1024
    unsigned* cnt2     = cursors + 1024;                         // pad 20480
    unsigned* bases    = cnt2 + 20480;                           // NBINS2+1, pad 20480
    unsigned* cursors2 = bases + 20480;                          // pad 20480
    size_t needed = 16000000ull + (size_t)NB * CAP * 8 + 4096 + 3ull * 81920;

    // Regrouped compact records live in d_out (dead until finalize).
    uint2* rec2 = (uint2*)d_out;

    if (ws_size >= needed) {
        init_cursors<<<1, 256, 0, stream>>>(cursors);
        zero_kernel<<<2048, 256, 0, stream>>>(f, 4 * N_USERS);      // hop flush is atomicAdd
        zero_kernel<<<80, 256, 0, stream>>>((float*)cnt2, NBINS2);  // bit-zero uints
        scatter_bin<<<SCAT_BLOCKS, 256, 0, stream>>>(src, dst, ew, rec, cursors);
        count_bins<<<NB * 4, 256, 0, stream>>>(rec, cursors, cnt2);
        prefix_bins<<<1, 256, 0, stream>>>(cnt2, bases, cursors2);
        regroup<<<RGRID, 256, 0, stream>>>(rec, cursors, rec2, cursors2);
        const float* cur = x;
        for (int h = 0; h < 4; ++h) {
            float* nxt = f + (size_t)h * N_USERS;
            hop_super<<<NSUP * HSPLIT, 512, 0, stream>>>(rec2, bases, cur, nxt);
            cur = nxt;
        }
    } else {
        zero_kernel<<<4096, 256, 0, stream>>>(f, 4 * N_USERS);
        const float* cur = x;
        for (int h = 0; h < 4; ++h) {
            float* nxt = f + (size_t)h * N_USERS;
            hop_atomic<<<NEDGE / 4 / 256, 256, 0, stream>>>(src, dst, ew, cur, nxt);
            cur = nxt;
        }
    }

    finalize_kernel<<<2048, 256, 0, stream>>>(
        x, f, f + N_USERS, f + 2 * N_USERS, f + 3 * N_USERS,
        W, bias, gamma, beta, out);
}

// Round 20
// 1604.675 us; speedup vs baseline: 1.0992x; 1.0992x over previous
//
#include <hip/hip_runtime.h>

#define N_USERS 1000000
#define NEDGE   32000000
#define OUT_F   64
#define BN_EPS  1e-5f

// Destination binning geometry (1D, round-12 architecture — best measured).
// The hop is pinned at ~0.22-0.24 records/cyc/CU across FIVE gather
// mechanisms (MSHR-miss, LDS-staged, L1-window, L1-resident-barriered,
// deep-MLP): a per-CU divergent-access processing wall. The regroup/window
// pass-2 architecture (rounds 14-19) pays ~380us to make hops NO faster ->
// reverted. This round: round-12 exact + two occupancy fixes (sbkt uchar:
// scatter LDS 44->40KB; SPLIT 8->10: hop grid 9.6 blocks/CU).
#define SBITS     12
#define S_BUCKET  4096
#define NB        245                     // ceil(N_USERS / S_BUCKET)
#define CAP       136896                  // mean 130612 + ~17 sigma, mult of 16
#define SCAT_BLOCKS 1024
#define TILE      4096                    // edges per scatter tile (LDS-sorted)
#define NTILES    ((NEDGE + TILE - 1) / TILE)
#define SPLIT     10                      // blocks per bucket in the hop

typedef unsigned int uint4v __attribute__((ext_vector_type(4)));
typedef int          int4v  __attribute__((ext_vector_type(4)));
typedef float        flt4v  __attribute__((ext_vector_type(4)));

// ---------------- binned path ----------------

__global__ void init_cursors(unsigned* __restrict__ cursors) {
    int i = blockIdx.x * blockDim.x + threadIdx.x;
    if (i < NB) cursors[i] = (unsigned)i * CAP;
}

// Tile-sorted scatter: counting-sort a 4096-edge tile by dst bucket in LDS,
// reserve one contiguous global range per (tile,bucket), flush coalesced runs.
// Vector nt loads issued up-front (round-12: 512->233us from this MLP).
// sbkt is uchar (NB=245 < 256): LDS 44->40KB -> +1 resident block/CU.
__global__ __launch_bounds__(256) void scatter_bin(
    const int* __restrict__ src, const int* __restrict__ dst,
    const float* __restrict__ ew, uint2* __restrict__ rec,
    unsigned* __restrict__ cursors) {
    __shared__ uint2 srec[TILE];             // 32KB tile records, bucket-sorted
    __shared__ unsigned char sbkt[TILE];     // 4KB bucket id per sorted pos
    __shared__ unsigned hist[NB];
    __shared__ unsigned curs[NB];
    __shared__ unsigned gpos[NB];
    __shared__ unsigned chunkT[256];
    int tid = threadIdx.x;

    for (int tile = blockIdx.x; tile < NTILES; tile += gridDim.x) {
        int e0 = tile * TILE;
        int n_this = (e0 + TILE <= NEDGE) ? TILE : (NEDGE - e0);  // mult of 4
        int nq = n_this >> 2;                                     // int4 count
        int q0 = e0 >> 2;

        for (int i = tid; i < NB; i += 256) hist[i] = 0;
        __syncthreads();

        int4v dv[4]; int4v sv[4]; flt4v wv[4];
        #pragma unroll
        for (int k = 0; k < 4; ++k) {
            int q = k * 256 + tid;
            if (q < nq) {
                dv[k] = __builtin_nontemporal_load(reinterpret_cast<const int4v*>(dst) + q0 + q);
                sv[k] = __builtin_nontemporal_load(reinterpret_cast<const int4v*>(src) + q0 + q);
                wv[k] = __builtin_nontemporal_load(reinterpret_cast<const flt4v*>(ew) + q0 + q);
            }
        }
        #pragma unroll
        for (int k = 0; k < 4; ++k) {
            int q = k * 256 + tid;
            if (q < nq) {
                #pragma unroll
                for (int j = 0; j < 4; ++j)
                    atomicAdd(&hist[dv[k][j] >> SBITS], 1u);
            }
        }
        __syncthreads();

        // parallel exclusive scan over hist[NB]
        {
            int base = tid * 4;
            unsigned run = 0;
            #pragma unroll
            for (int k = 0; k < 4; ++k) {
                int idx = base + k;
                unsigned v = (idx < NB) ? hist[idx] : 0u;
                if (idx < NB) hist[idx] = run;
                run += v;
            }
            chunkT[tid] = run;
        }
        __syncthreads();
        if (tid == 0) {
            unsigned r = 0;
            for (int t = 0; t < 256; ++t) { unsigned v = chunkT[t]; chunkT[t] = r; r += v; }
        }
        __syncthreads();
        {
            int base = tid * 4;
            unsigned add = chunkT[tid];
            #pragma unroll
            for (int k = 0; k < 4; ++k) {
                int idx = base + k;
                if (idx < NB) hist[idx] += add;
            }
        }
        __syncthreads();

        for (int b = tid; b < NB; b += 256) {
            unsigned st = hist[b];
            unsigned en = (b == NB - 1) ? (unsigned)n_this : hist[b + 1];
            unsigned c = en - st;
            gpos[b] = c ? atomicAdd(&cursors[b], c) : 0u;
            curs[b] = 0;
        }
        __syncthreads();

        #pragma unroll
        for (int k = 0; k < 4; ++k) {
            int q = k * 256 + tid;
            if (q < nq) {
                #pragma unroll
                for (int j = 0; j < 4; ++j) {
                    int dd = dv[k][j], ss = sv[k][j];
                    int b = dd >> SBITS;
                    unsigned p = hist[b] + atomicAdd(&curs[b], 1u);
                    srec[p] = make_uint2(((unsigned)(dd & (S_BUCKET - 1)) << 20) | (unsigned)ss,
                                         __float_as_uint(wv[k][j]));
                    sbkt[p] = (unsigned char)b;
                }
            }
        }
        __syncthreads();

        for (int i = tid; i < n_this; i += 256) {   // coalesced segment flush
            unsigned b = sbkt[i];
            rec[gpos[b] + ((unsigned)i - hist[b])] = srec[i];
        }
        __syncthreads();                            // before next tile reuses LDS
    }
}

// LDS-accumulation hop (round-12 proven): SPLIT blocks per 4096-node bucket;
// stream records (nt), gather cur[src], ds_add_f32 into 16KB accumulator,
// coalesced global atomicAdd flush (nxt pre-zeroed). 8 records/iter (4x uint4
// nt loads) = 8 independent gathers in flight per lane. SPLIT=10 -> grid 2450
// (~9.6 blocks/CU >= 8 resident max) for full wave-slot occupancy.
__global__ __launch_bounds__(256) void hop_bucket(
    const uint2* __restrict__ rec, const unsigned* __restrict__ cursors,
    const float* __restrict__ cur, float* __restrict__ nxt) {
    __shared__ float acc[S_BUCKET];
    int tid = threadIdx.x;
    int b = blockIdx.x / SPLIT;
    int sidx = blockIdx.x % SPLIT;
    for (int i = tid; i < S_BUCKET; i += 256) acc[i] = 0.0f;
    __syncthreads();

    unsigned start = (unsigned)b * CAP;          // CAP mult of 8 -> 64B aligned
    unsigned cnt = cursors[b] - start;
    unsigned u0 = ((cnt * (unsigned)sidx) / SPLIT) & ~7u;
    unsigned u1 = (sidx == SPLIT - 1) ? cnt : (((cnt * (unsigned)(sidx + 1)) / SPLIT) & ~7u);
    const uint2* bp = rec + start;

    unsigned i = u0 + 8u * (unsigned)tid;
    for (; i + 8u <= u1; i += 8u * 256u) {
        uint4v r0 = __builtin_nontemporal_load(reinterpret_cast<const uint4v*>(bp + i));
        uint4v r1 = __builtin_nontemporal_load(reinterpret_cast<const uint4v*>(bp + i + 2));
        uint4v r2 = __builtin_nontemporal_load(reinterpret_cast<const uint4v*>(bp + i + 4));
        uint4v r3 = __builtin_nontemporal_load(reinterpret_cast<const uint4v*>(bp + i + 6));
        float c0 = cur[r0.x & 0xFFFFFu];
        float c1 = cur[r0.z & 0xFFFFFu];
        float c2 = cur[r1.x & 0xFFFFFu];
        float c3 = cur[r1.z & 0xFFFFFu];
        float c4 = cur[r2.x & 0xFFFFFu];
        float c5 = cur[r2.z & 0xFFFFFu];
        float c6 = cur[r3.x & 0xFFFFFu];
        float c7 = cur[r3.z & 0xFFFFFu];
        atomicAdd(&acc[r0.x >> 20], c0 * __uint_as_float(r0.y));
        atomicAdd(&acc[r0.z >> 20], c1 * __uint_as_float(r0.w));
        atomicAdd(&acc[r1.x >> 20], c2 * __uint_as_float(r1.y));
        atomicAdd(&acc[r1.z >> 20], c3 * __uint_as_float(r1.w));
        atomicAdd(&acc[r2.x >> 20], c4 * __uint_as_float(r2.y));
        atomicAdd(&acc[r2.z >> 20], c5 * __uint_as_float(r2.w));
        atomicAdd(&acc[r3.x >> 20], c6 * __uint_as_float(r3.y));
        atomicAdd(&acc[r3.z >> 20], c7 * __uint_as_float(r3.w));
    }
    if (i < u1) {                                // straddling remainder (<8), one thread
        for (unsigned j = i; j < i + 8u && j < u1; ++j) {
            uint2 r = bp[j];
            atomicAdd(&acc[r.x >> 20], cur[r.x & 0xFFFFFu] * __uint_as_float(r.y));
        }
    }
    __syncthreads();

    int nb0 = b << SBITS;
    for (int k = tid; k < S_BUCKET; k += 256) {
        int n = nb0 + k;
        if (n < N_USERS) atomicAdd(&nxt[n], acc[k]);
    }
}

// ---------------- fallback path (device atomics, small workspace) ----------------

__global__ void zero_kernel(float* __restrict__ p, int n) {
    int i = blockIdx.x * blockDim.x + threadIdx.x;
    int stride = gridDim.x * blockDim.x;
    for (; i < n; i += stride) p[i] = 0.0f;
}

__global__ __launch_bounds__(256) void hop_atomic(
    const int* __restrict__ src, const int* __restrict__ dst,
    const float* __restrict__ ew, const float* __restrict__ cur,
    float* __restrict__ nxt) {
    int e = blockIdx.x * blockDim.x + threadIdx.x;
    if (e * 4 < NEDGE) {
        int4   s = ((const int4*)src)[e];
        int4   d = ((const int4*)dst)[e];
        float4 w = ((const float4*)ew)[e];
        atomicAdd(&nxt[d.x], cur[s.x] * w.x);
        atomicAdd(&nxt[d.y], cur[s.y] * w.y);
        atomicAdd(&nxt[d.z], cur[s.z] * w.z);
        atomicAdd(&nxt[d.w], cur[s.w] * w.w);
    }
}

// ---------------- finalize: 5->64 matvec + BatchNorm over features ----------------

__global__ __launch_bounds__(256) void finalize_kernel(
    const float* __restrict__ x,  const float* __restrict__ f1,
    const float* __restrict__ f2, const float* __restrict__ f3,
    const float* __restrict__ f4, const float* __restrict__ W,
    const float* __restrict__ bias, const float* __restrict__ gamma,
    const float* __restrict__ beta, float* __restrict__ out) {
    int lane = threadIdx.x & 63;
    int waveInBlock = threadIdx.x >> 6;
    int wavesPerBlock = blockDim.x >> 6;
    int gwave  = blockIdx.x * wavesPerBlock + waveInBlock;
    int nwaves = gridDim.x * wavesPerBlock;

    float w0 = W[lane * 5 + 0];
    float w1 = W[lane * 5 + 1];
    float w2 = W[lane * 5 + 2];
    float w3 = W[lane * 5 + 3];
    float w4 = W[lane * 5 + 4];
    float b  = bias[lane];

    for (int n = gwave; n < N_USERS; n += nwaves) {
        float c0 = x[n], c1 = f1[n], c2 = f2[n], c3 = f3[n], c4 = f4[n];
        float y = b + c0 * w0 + c1 * w1 + c2 * w2 + c3 * w3 + c4 * w4;

        float s = y;
        #pragma unroll
        for (int off = 32; off; off >>= 1) s += __shfl_xor(s, off);
        float mean = s * (1.0f / 64.0f);

        float d = y - mean;
        float v = d * d;
        #pragma unroll
        for (int off = 32; off; off >>= 1) v += __shfl_xor(v, off);
        float var = v * (1.0f / 64.0f);

        float o = d * rsqrtf(var + BN_EPS) * gamma[n] + beta[n];
        __builtin_nontemporal_store(o, &out[(size_t)n * OUT_F + lane]);
    }
}

extern "C" void kernel_launch(void* const* d_in, const int* in_sizes, int n_in,
                              void* d_out, int out_size, void* d_ws, size_t ws_size,
                              hipStream_t stream) {
    const float* x     = (const float*)d_in[0];
    const int*   ei    = (const int*)d_in[1];
    const float* ew    = (const float*)d_in[2];
    const float* W     = (const float*)d_in[3];
    const float* bias  = (const float*)d_in[4];
    const float* gamma = (const float*)d_in[5];
    const float* beta  = (const float*)d_in[6];
    float* out = (float*)d_out;

    const int* src = ei;
    const int* dst = ei + NEDGE;

    // Workspace layout (total ~284.3MB; known-available >= 304MB from rounds 0-1)
    float* f = (float*)d_ws;                                   // 16MB
    uint2* rec = (uint2*)(f + 4ull * N_USERS);                 // 268.3MB (padded)
    unsigned* cursors = (unsigned*)(rec + (size_t)NB * CAP);   // 4KB
    size_t needed = 16000000ull + (size_t)NB * CAP * 8 + 4096;

    if (ws_size >= needed) {
        init_cursors<<<1, 256, 0, stream>>>(cursors);
        zero_kernel<<<2048, 256, 0, stream>>>(f, 4 * N_USERS);   // hop flush is atomicAdd
        scatter_bin<<<SCAT_BLOCKS, 256, 0, stream>>>(src, dst, ew, rec, cursors);
        const float* cur = x;
        for (int h = 0; h < 4; ++h) {
            float* nxt = f + (size_t)h * N_USERS;
            hop_bucket<<<NB * SPLIT, 256, 0, stream>>>(rec, cursors, cur, nxt);
            cur = nxt;
        }
    } else {
        zero_kernel<<<4096, 256, 0, stream>>>(f, 4 * N_USERS);
        const float* cur = x;
        for (int h = 0; h < 4; ++h) {
            float* nxt = f + (size_t)h * N_USERS;
            hop_atomic<<<NEDGE / 4 / 256, 256, 0, stream>>>(src, dst, ew, cur, nxt);
            cur = nxt;
        }
    }

    finalize_kernel<<<2048, 256, 0, stream>>>(
        x, f, f + N_USERS, f + 2 * N_USERS, f + 3 * N_USERS,
        W, bias, gamma, beta, out);
}